// Round 4
// baseline (898.344 us; speedup 1.0000x reference)
//
#include <hip/hip_runtime.h>

// PFCAttention on MI355X (gfx950). Round 4 (= round 3 + cvt_pkrtz type fix).
// B=16, H=W=64, C=512, WS=8 -> N=64 tok/window, nWs=64, B_=1024, NH=16, hd=32.
//
//  - QKV GEMM reads X fp32 directly (fp32 LDS stage + cvt_pkrtz on LDS->reg path).
//  - Pooling fused into QKV GEMM epilogue (shfl reduce of accumulators).
//  - Attention + final projection fused (cat buffer eliminated): per window, per head:
//    attention -> 64x64 cat-slice in LDS -> accumulate persistent 64x512 fp32
//    out-accumulator vs WcT head-slice (L2-resident).
//  - All 128B-row LDS tiles chunk-XOR swizzled (writer+reader, both-sides).
//
// Workspace (bytes), total ~197 MiB:
//   qb 0 / kb 67108864 / vb 134217728      (64 MiB each, fp16 [B_*NH][64][32])
//   qwT 201326592  (1.5 MiB fp16 [1536][512])
//   WcT 202899456  (1 MiB fp16 [512][1024])
//   bc  203948032  (2 KiB fp32[512]) lbf 203950080 / gbf 204212224 (256 KiB each)
//   Kgb 204474368  (1 MiB fp16 [B*NH][64][32])  Vgt 205522944 (1 MiB fp16 [B*NH][32][64])

typedef unsigned int u32;
typedef unsigned short u16;
typedef _Float16 f16;
typedef __attribute__((ext_vector_type(8))) _Float16 f16x8;
typedef __attribute__((ext_vector_type(4))) float f32x4;
typedef __fp16 fp16x2 __attribute__((ext_vector_type(2)));
typedef __attribute__((ext_vector_type(4))) u32 u32x4;

__device__ __forceinline__ f32x4 mfma_16x16x32(f16x8 a, f16x8 b, f32x4 c) {
  return __builtin_amdgcn_mfma_f32_16x16x32_f16(a, b, c, 0, 0, 0);
}

__device__ __forceinline__ void async_cp16(const void* g, void* l) {
  __builtin_amdgcn_global_load_lds(
      (const __attribute__((address_space(1))) u32*)g,
      (__attribute__((address_space(3))) u32*)l, 16, 0, 0);
}

__device__ __forceinline__ f16x8 cvt8_rtz(const float4 a, const float4 b) {
  u32x4 w;
  w[0] = __builtin_bit_cast(u32, __builtin_amdgcn_cvt_pkrtz(a.x, a.y));
  w[1] = __builtin_bit_cast(u32, __builtin_amdgcn_cvt_pkrtz(a.z, a.w));
  w[2] = __builtin_bit_cast(u32, __builtin_amdgcn_cvt_pkrtz(b.x, b.y));
  w[3] = __builtin_bit_cast(u32, __builtin_amdgcn_cvt_pkrtz(b.z, b.w));
  return __builtin_bit_cast(f16x8, w);
}

// ---------------------------------------------------------------------------
// Prep kernels
// ---------------------------------------------------------------------------

__global__ void k_biastab(const float* __restrict__ ltab, const float* __restrict__ gtab,
                          float* __restrict__ lbf, float* __restrict__ gbf) {
  const int id = blockIdx.x * 256 + threadIdx.x;   // 0..8191
  const int pair = id & 4095;
  const int n = pair >> 6, m = pair & 63;
  const int yn = n >> 3, xn = n & 7;
  const int ym = m >> 3, xm = m & 7;
  const int idx = (yn - ym + 7) * 15 + (xn - xm + 7);
  if (id < 4096) {
#pragma unroll
    for (int h = 0; h < 16; ++h) lbf[h * 4096 + pair] = ltab[idx * 16 + h];
  } else {
#pragma unroll
    for (int h = 0; h < 16; ++h) gbf[h * 4096 + pair] = gtab[idx * 16 + h];
  }
}

__global__ void k_tqkvw(const float* __restrict__ w, f16* __restrict__ wT) {
  __shared__ f16 sT[64][72];
  const int bid = blockIdx.x;
  const int k0 = (bid / 24) * 64, n0 = (bid % 24) * 64;
  const int t = threadIdx.x;
#pragma unroll
  for (int p = 0; p < 4; ++p) {
    const int kl = p * 16 + (t >> 4), nl = (t & 15) * 4;
    const float4 v = *reinterpret_cast<const float4*>(w + (size_t)(k0 + kl) * 1536 + n0 + nl);
    sT[kl][nl] = (f16)v.x; sT[kl][nl + 1] = (f16)v.y;
    sT[kl][nl + 2] = (f16)v.z; sT[kl][nl + 3] = (f16)v.w;
  }
  __syncthreads();
#pragma unroll
  for (int q = 0; q < 2; ++q) {
    const int nl = q * 32 + (t >> 3), kl = (t & 7) * 8;
    f16x8 r;
#pragma unroll
    for (int j = 0; j < 8; ++j) r[j] = sT[kl + j][nl];
    *reinterpret_cast<f16x8*>(wT + (size_t)(n0 + nl) * 512 + k0 + kl) = r;
  }
}

__global__ __launch_bounds__(256) void k_compose(const float* __restrict__ lpw,
                                                 const float* __restrict__ gpw,
                                                 const float* __restrict__ pfc_w,
                                                 f16* __restrict__ WT) {
  __shared__ float sW[16][16];
  const int kk0 = blockIdx.x * 16;
  const bool top = kk0 < 512;
  const float* src = top ? (lpw + kk0 * 512) : (gpw + (kk0 - 512) * 512);
  const float* pf = pfc_w + (top ? 0 : 512 * 512);
  const int t = threadIdx.x;
  float acc0[16], acc1[16];
#pragma unroll
  for (int i = 0; i < 16; ++i) { acc0[i] = 0.f; acc1[i] = 0.f; }
  for (int ct = 0; ct < 32; ++ct) {
    sW[t >> 4][t & 15] = src[(t >> 4) * 512 + ct * 16 + (t & 15)];
    __syncthreads();
#pragma unroll
    for (int cc = 0; cc < 16; ++cc) {
      const int c = ct * 16 + cc;
      const float p0 = pf[c * 512 + t];
      const float p1 = pf[c * 512 + t + 256];
#pragma unroll
      for (int i = 0; i < 16; ++i) { acc0[i] += sW[i][cc] * p0; acc1[i] += sW[i][cc] * p1; }
    }
    __syncthreads();
  }
#pragma unroll
  for (int i = 0; i < 16; ++i) WT[(size_t)t * 1024 + kk0 + i] = (f16)acc0[i];
#pragma unroll
  for (int i = 0; i < 16; ++i) WT[(size_t)(t + 256) * 1024 + kk0 + i] = (f16)acc1[i];
}

__global__ void k_bc_init(const float* __restrict__ pfc_b, float* __restrict__ bc) {
  const int j = blockIdx.x * 256 + threadIdx.x;
  bc[j] = pfc_b[j];
}

__global__ void k_bc_acc(const float* __restrict__ lpb, const float* __restrict__ gpb,
                         const float* __restrict__ pfc_w, float* __restrict__ bc) {
  const int t = threadIdx.x;
  const int c0 = blockIdx.x * 32;
  float p0 = 0.f, p1 = 0.f;
#pragma unroll
  for (int i = 0; i < 32; ++i) {
    const int c = c0 + i;
    const float wgt = (c < 512) ? lpb[c] : gpb[c - 512];
    p0 += wgt * pfc_w[(size_t)c * 512 + t];
    p1 += wgt * pfc_w[(size_t)c * 512 + t + 256];
  }
  atomicAdd(bc + t, p0);
  atomicAdd(bc + t + 256, p1);
}

// ---------------------------------------------------------------------------
// QKV GEMM + fused pooling. X read as fp32, converted on LDS->reg path.
// 256x128 tile, 8 waves (4r x 2c), K-step 32, XCD-chunked swizzle. grid 3072 x 512.
// ---------------------------------------------------------------------------
__global__ __launch_bounds__(512, 2) void k_gemm_qkv(const float* __restrict__ X,
                                                     const f16* __restrict__ BT,
                                                     const float* __restrict__ qkv_b,
                                                     const float* __restrict__ pool_w,
                                                     const float* __restrict__ pool_b,
                                                     f16* __restrict__ qb,
                                                     f16* __restrict__ kb,
                                                     f16* __restrict__ vb,
                                                     f16* __restrict__ Kgb,
                                                     f16* __restrict__ Vgt) {
  __shared__ float sA[8192];   // [256 rows][8 chunks x 4 floats], chunk ^= row&7
  __shared__ f16 sB[4096];     // [128 rows][4 chunks x 8 f16],    chunk ^= row&3
  const int wid = (blockIdx.x & 7) * 384 + (blockIdx.x >> 3);
  const int br = wid / 12, bn = wid % 12;
  const int t = threadIdx.x;
  const int wv = t >> 6, l = t & 63, lr = l & 15, lk = l >> 4;
  const int wvr = wv >> 1, wvc = wv & 1;

  f32x4 acc[4][4] = {};

  const int arow = t >> 3;
  const int afc = ((t & 7) ^ (arow & 7)) * 4;
  const float* gA = X + (size_t)(br * 256 + arow) * 512 + afc;
  const int brow = t >> 2;
  const int bfc = ((t & 3) ^ (brow & 3)) * 8;
  const f16* gB = BT + (size_t)(bn * 128 + brow) * 512 + bfc;

  for (int kk = 0; kk < 16; ++kk) {
#pragma unroll
    for (int i = 0; i < 4; ++i)
      async_cp16(gA + (size_t)(i * 64) * 512 + kk * 32, &sA[(i * 512 + t) * 4]);
    async_cp16(gB + kk * 32, &sB[t * 8]);
    __syncthreads();
    f16x8 af[4], bf[4];
#pragma unroll
    for (int m = 0; m < 4; ++m) {
      const int row = wvr * 64 + m * 16 + lr;
      const int c0 = (2 * lk) ^ (lr & 7), c1 = (2 * lk + 1) ^ (lr & 7);
      const float4 v0 = *reinterpret_cast<const float4*>(&sA[row * 32 + c0 * 4]);
      const float4 v1 = *reinterpret_cast<const float4*>(&sA[row * 32 + c1 * 4]);
      af[m] = cvt8_rtz(v0, v1);
    }
#pragma unroll
    for (int n = 0; n < 4; ++n) {
      const int row = wvc * 64 + n * 16 + lr;
      bf[n] = *reinterpret_cast<const f16x8*>(&sB[row * 32 + ((lk ^ (lr & 3)) * 8)]);
    }
#pragma unroll
    for (int m = 0; m < 4; ++m)
#pragma unroll
      for (int n = 0; n < 4; ++n) acc[m][n] = mfma_16x16x32(af[m], bf[n], acc[m][n]);
    __syncthreads();
  }

  // epilogue: scatter q/k/v + fused pooling (wave's 64 rows = one window)
  const int w_idx = br * 4 + wvr;
  const int bb = w_idx >> 6, ww = w_idx & 63;
  float pw[4][4];
#pragma unroll
  for (int m = 0; m < 4; ++m)
#pragma unroll
    for (int r = 0; r < 4; ++r) pw[m][r] = pool_w[m * 16 + lk * 4 + r];
  const float pb = pool_b[0];

#pragma unroll
  for (int n = 0; n < 4; ++n) {
    const int col = bn * 128 + wvc * 64 + n * 16 + lr;   // 0..1535
    const int which = col >> 9;
    const int hh = (col >> 5) & 15, d = col & 31;
    const float bias = qkv_b[col];
    f16* dst = which == 0 ? qb : (which == 1 ? kb : vb);
#pragma unroll
    for (int m = 0; m < 4; ++m)
#pragma unroll
      for (int r = 0; r < 4; ++r) {
        const int row = br * 256 + wvr * 64 + m * 16 + lk * 4 + r;
        dst[(size_t)(((row >> 6) << 4) + hh) * 2048 + (row & 63) * 32 + d] =
            (f16)(acc[m][n][r] + bias);
      }
    if (which != 0) {
      float part = 0.f;
#pragma unroll
      for (int m = 0; m < 4; ++m)
#pragma unroll
        for (int r = 0; r < 4; ++r) part += (acc[m][n][r] + bias) * pw[m][r];
      part += __shfl_xor(part, 16);
      part += __shfl_xor(part, 32);
      part += pb;
      if (lk == 0) {
        if (which == 1)
          Kgb[((size_t)(bb * 16 + hh) * 64 + ww) * 32 + d] = (f16)part;
        else
          Vgt[((size_t)(bb * 16 + hh) * 32 + d) * 64 + ww] = (f16)part;
      }
    }
  }
}

// ---------------------------------------------------------------------------
// Fused attention + projection. One block per window b_ (1024 blocks x 512 thr).
// ---------------------------------------------------------------------------
__global__ __launch_bounds__(512, 2) void k_attn_proj(const f16* __restrict__ qb,
                                                      const f16* __restrict__ kb,
                                                      const f16* __restrict__ vb,
                                                      const f16* __restrict__ Kgb,
                                                      const f16* __restrict__ Vgt,
                                                      const float* __restrict__ lbf,
                                                      const float* __restrict__ gbf,
                                                      const f16* __restrict__ WcT,
                                                      const float* __restrict__ bc,
                                                      float* __restrict__ out) {
  __shared__ f16 sVraw[2048];  // [64 tok][32 d]
  __shared__ f16 sVt[2048];    // [32 d][8 chunks x 8 tok], chunk ^= d&7
  __shared__ f16 sP[8192];     // [128 rows][8 chunks x 8], chunk ^= row&7
  __shared__ f16 sCat[4096];   // [64 rows][8 chunks x 8],  chunk ^= row&7
  const int b_ = blockIdx.x;
  const int b = b_ >> 6;
  const int t = threadIdx.x;
  const int wv = t >> 6, l = t & 63, lr = l & 15, lk = l >> 4;
  const int wvq = wv & 3;
  const bool fine = wv < 4;
  const int wvM = wv & 1, wvN = wv >> 1;
  const float scale = 0.17677669529663687f;

  f32x4 acc[2][8] = {};

  for (int h = 0; h < 16; ++h) {
    const size_t hs = ((size_t)b_ * 16 + h) * 2048;
    const size_t gs = ((size_t)b * 16 + h);
    if (t < 256) async_cp16(vb + hs + t * 8, &sVraw[t * 8]);
    __syncthreads();
    if (t < 256) {
      const int d = t >> 3, tok0 = (t & 7) << 3;
      f16x8 w;
#pragma unroll
      for (int j = 0; j < 8; ++j) w[j] = sVraw[(tok0 + j) * 32 + d];
      *reinterpret_cast<f16x8*>(&sVt[d * 64 + (((t & 7) ^ (d & 7)) << 3)]) = w;
    }

    // ---- QK^T (+bias, softmax) ----
    const f16x8 aq = *reinterpret_cast<const f16x8*>(qb + hs + (wvq * 16 + lr) * 32 + lk * 8);
    float p[4][4], inv[4];
    {
      f32x4 s[4];
#pragma unroll
      for (int j = 0; j < 4; ++j) {
        const f16x8 bk = fine
            ? *reinterpret_cast<const f16x8*>(kb + hs + (j * 16 + lr) * 32 + lk * 8)
            : *reinterpret_cast<const f16x8*>(Kgb + (gs * 64 + j * 16 + lr) * 32 + lk * 8);
        f32x4 z = {};
        s[j] = mfma_16x16x32(aq, bk, z);
      }
      const float* bt = (fine ? lbf : gbf) + h * 4096 + (wvq * 16 + lk * 4) * 64;
#pragma unroll
      for (int r = 0; r < 4; ++r) {
        float m = -1e30f;
#pragma unroll
        for (int j = 0; j < 4; ++j) {
          const float v = s[j][r] * scale + bt[r * 64 + j * 16 + lr];
          p[j][r] = v;
          m = fmaxf(m, v);
        }
        m = fmaxf(m, __shfl_xor(m, 1));
        m = fmaxf(m, __shfl_xor(m, 2));
        m = fmaxf(m, __shfl_xor(m, 4));
        m = fmaxf(m, __shfl_xor(m, 8));
        float su = 0.f;
#pragma unroll
        for (int j = 0; j < 4; ++j) {
          const float e = __expf(p[j][r] - m);
          p[j][r] = e;
          su += e;
        }
        su += __shfl_xor(su, 1);
        su += __shfl_xor(su, 2);
        su += __shfl_xor(su, 4);
        su += __shfl_xor(su, 8);
        inv[r] = 1.f / su;
      }
    }
#pragma unroll
    for (int r = 0; r < 4; ++r) {
      const int rowP = wv * 16 + lk * 4 + r;
#pragma unroll
      for (int j = 0; j < 4; ++j) {
        const int col = j * 16 + lr;
        sP[rowP * 64 + (((col >> 3) ^ (rowP & 7)) << 3) + (col & 7)] = (f16)p[j][r];
      }
    }
    __syncthreads();

    // ---- PV ----
    {
      const int rowP = wv * 16 + lr;
      const f16x8 a0 = *reinterpret_cast<const f16x8*>(&sP[rowP * 64 + ((lk ^ (lr & 7)) << 3)]);
      const f16x8 a1 = *reinterpret_cast<const f16x8*>(&sP[rowP * 64 + (((4 + lk) ^ (lr & 7)) << 3)]);
#pragma unroll
      for (int n = 0; n < 2; ++n) {
        f16x8 b0, b1;
        if (fine) {
          const int d = n * 16 + lr;
          b0 = *reinterpret_cast<const f16x8*>(&sVt[d * 64 + ((lk ^ (d & 7)) << 3)]);
          b1 = *reinterpret_cast<const f16x8*>(&sVt[d * 64 + (((4 + lk) ^ (d & 7)) << 3)]);
        } else {
          const f16* vp = Vgt + (gs * 32 + n * 16 + lr) * 64 + lk * 8;
          b0 = *reinterpret_cast<const f16x8*>(vp);
          b1 = *reinterpret_cast<const f16x8*>(vp + 32);
        }
        f32x4 o = {};
        o = mfma_16x16x32(a0, b0, o);
        o = mfma_16x16x32(a1, b1, o);
#pragma unroll
        for (int r = 0; r < 4; ++r) {
          const int rowC = wvq * 16 + lk * 4 + r;
          const int colC = (fine ? 0 : 32) + n * 16 + lr;
          sCat[rowC * 64 + (((colC >> 3) ^ (rowC & 7)) << 3) + (colC & 7)] =
              (f16)(o[r] * inv[r]);
        }
      }
    }
    __syncthreads();

    // ---- projection accumulate ----
    f16x8 a[2][2];
#pragma unroll
    for (int m = 0; m < 2; ++m) {
      const int rowA = wvM * 32 + m * 16 + lr;
#pragma unroll
      for (int kh = 0; kh < 2; ++kh)
        a[m][kh] = *reinterpret_cast<const f16x8*>(
            &sCat[rowA * 64 + (((kh * 4 + lk) ^ (rowA & 7)) << 3)]);
    }
#pragma unroll
    for (int n = 0; n < 8; ++n) {
      const int col = wvN * 128 + n * 16 + lr;
      const f16* wp = WcT + (size_t)col * 1024 + h * 32 + lk * 8;
      const f16x8 b0 = *reinterpret_cast<const f16x8*>(wp);
      const f16x8 b1 = *reinterpret_cast<const f16x8*>(wp + 512);
#pragma unroll
      for (int m = 0; m < 2; ++m) {
        acc[m][n] = mfma_16x16x32(a[m][0], b0, acc[m][n]);
        acc[m][n] = mfma_16x16x32(a[m][1], b1, acc[m][n]);
      }
    }
    __syncthreads();
  }

  // epilogue
#pragma unroll
  for (int n = 0; n < 8; ++n) {
    const int col = wvN * 128 + n * 16 + lr;
    const float bias = bc[col];
#pragma unroll
    for (int m = 0; m < 2; ++m)
#pragma unroll
      for (int r = 0; r < 4; ++r) {
        const int row = b_ * 64 + wvM * 32 + m * 16 + lk * 4 + r;
        out[(size_t)row * 512 + col] = acc[m][n][r] + bias;
      }
  }
}

// ---------------------------------------------------------------------------

extern "C" void kernel_launch(void* const* d_in, const int* in_sizes, int n_in,
                              void* d_out, int out_size, void* d_ws, size_t ws_size,
                              hipStream_t stream) {
  const float* x      = (const float*)d_in[0];
  const float* qkv_w  = (const float*)d_in[1];
  const float* qkv_b  = (const float*)d_in[2];
  const float* ltab   = (const float*)d_in[3];
  const float* gtab   = (const float*)d_in[4];
  const float* lpw    = (const float*)d_in[5];
  const float* lpb    = (const float*)d_in[6];
  const float* pool_w = (const float*)d_in[7];
  const float* pool_b = (const float*)d_in[8];
  const float* gpw    = (const float*)d_in[9];
  const float* gpb    = (const float*)d_in[10];
  const float* pfc_w  = (const float*)d_in[11];
  const float* pfc_b  = (const float*)d_in[12];
  float* out = (float*)d_out;

  char* ws = (char*)d_ws;
  f16*   qb   = (f16*)(ws + 0);
  f16*   kb   = (f16*)(ws + 67108864);
  f16*   vb   = (f16*)(ws + 134217728);
  f16*   qwT  = (f16*)(ws + 201326592);
  f16*   WcT  = (f16*)(ws + 202899456);
  float* bc   = (float*)(ws + 203948032);
  float* lbf  = (float*)(ws + 203950080);
  float* gbf  = (float*)(ws + 204212224);
  f16*   Kgb  = (f16*)(ws + 204474368);
  f16*   Vgt  = (f16*)(ws + 205522944);

  k_biastab<<<32, 256, 0, stream>>>(ltab, gtab, lbf, gbf);
  k_tqkvw<<<192, 256, 0, stream>>>(qkv_w, qwT);
  k_compose<<<64, 256, 0, stream>>>(lpw, gpw, pfc_w, WcT);
  k_bc_init<<<2, 256, 0, stream>>>(pfc_b, bc);
  k_bc_acc<<<32, 256, 0, stream>>>(lpb, gpb, pfc_w, bc);
  k_gemm_qkv<<<3072, 512, 0, stream>>>(x, qwT, qkv_b, pool_w, pool_b,
                                       qb, kb, vb, Kgb, Vgt);
  k_attn_proj<<<1024, 512, 0, stream>>>(qb, kb, vb, Kgb, Vgt, lbf, gbf, WcT, bc, out);
}

// Round 5
// 545.900 us; speedup vs baseline: 1.6456x; 1.6456x over previous
//
#include <hip/hip_runtime.h>

// PFCAttention on MI355X (gfx950). Round 5.
// B=16, H=W=64, C=512, WS=8 -> N=64 tok/window, nWs=64, B_=1024, NH=16, hd=32.
//
// Round-5: revert round-4's mega-fusion (latency-bound, 1 block/CU). Split:
//  - k_gemm_qkv: unchanged from round 4 (fp32-direct A + fused pooling).
//  - k_attn: 1 block/(b_,h), 4 waves; Q/K/Kg/Vg frags direct from global (L2);
//    LDS only for V-transpose + P + cat tile, all XOR-swizzled; 2 barriers;
//    cat stored with permuted cols (h*64+half*32+d) as 128-B row segments.
//  - k_gemm_final: BK=64 (conflict-free 8-chunk XOR), 256x128 tile, XCD swizzle.
//  - k_compose emits WcT rows in the same permuted k-order (cancels in dot product).
//
// Workspace (bytes):
//   qb 0 / kb 67108864 / vb 134217728 (64 MiB each, fp16 [B_*NH][64][32])
//   cat 201326592 (128 MiB fp16 [65536][1024], cols h*64+half*32+d)
//   qwT 335544320 (1.5 MiB) WcT 337117184 (1 MiB) bc 338165760 (2 KiB)
//   lbf 338167808 / gbf 338429952 (256 KiB each)
//   Kgb 338692096 (1 MiB [B*NH][64][32])  Vgt 339740672 (1 MiB [B*NH][32][64])

typedef unsigned int u32;
typedef _Float16 f16;
typedef __attribute__((ext_vector_type(8))) _Float16 f16x8;
typedef __attribute__((ext_vector_type(4))) float f32x4;
typedef __attribute__((ext_vector_type(4))) u32 u32x4;

__device__ __forceinline__ f32x4 mfma_16x16x32(f16x8 a, f16x8 b, f32x4 c) {
  return __builtin_amdgcn_mfma_f32_16x16x32_f16(a, b, c, 0, 0, 0);
}

__device__ __forceinline__ void async_cp16(const void* g, void* l) {
  __builtin_amdgcn_global_load_lds(
      (const __attribute__((address_space(1))) u32*)g,
      (__attribute__((address_space(3))) u32*)l, 16, 0, 0);
}

__device__ __forceinline__ f16x8 cvt8_rtz(const float4 a, const float4 b) {
  u32x4 w;
  w[0] = __builtin_bit_cast(u32, __builtin_amdgcn_cvt_pkrtz(a.x, a.y));
  w[1] = __builtin_bit_cast(u32, __builtin_amdgcn_cvt_pkrtz(a.z, a.w));
  w[2] = __builtin_bit_cast(u32, __builtin_amdgcn_cvt_pkrtz(b.x, b.y));
  w[3] = __builtin_bit_cast(u32, __builtin_amdgcn_cvt_pkrtz(b.z, b.w));
  return __builtin_bit_cast(f16x8, w);
}

// ---------------------------------------------------------------------------
// Prep kernels
// ---------------------------------------------------------------------------

__global__ void k_biastab(const float* __restrict__ ltab, const float* __restrict__ gtab,
                          float* __restrict__ lbf, float* __restrict__ gbf) {
  const int id = blockIdx.x * 256 + threadIdx.x;   // 0..8191
  const int pair = id & 4095;
  const int n = pair >> 6, m = pair & 63;
  const int yn = n >> 3, xn = n & 7;
  const int ym = m >> 3, xm = m & 7;
  const int idx = (yn - ym + 7) * 15 + (xn - xm + 7);
  if (id < 4096) {
#pragma unroll
    for (int h = 0; h < 16; ++h) lbf[h * 4096 + pair] = ltab[idx * 16 + h];
  } else {
#pragma unroll
    for (int h = 0; h < 16; ++h) gbf[h * 4096 + pair] = gtab[idx * 16 + h];
  }
}

__global__ void k_tqkvw(const float* __restrict__ w, f16* __restrict__ wT) {
  __shared__ f16 sT[64][72];
  const int bid = blockIdx.x;
  const int k0 = (bid / 24) * 64, n0 = (bid % 24) * 64;
  const int t = threadIdx.x;
#pragma unroll
  for (int p = 0; p < 4; ++p) {
    const int kl = p * 16 + (t >> 4), nl = (t & 15) * 4;
    const float4 v = *reinterpret_cast<const float4*>(w + (size_t)(k0 + kl) * 1536 + n0 + nl);
    sT[kl][nl] = (f16)v.x; sT[kl][nl + 1] = (f16)v.y;
    sT[kl][nl + 2] = (f16)v.z; sT[kl][nl + 3] = (f16)v.w;
  }
  __syncthreads();
#pragma unroll
  for (int q = 0; q < 2; ++q) {
    const int nl = q * 32 + (t >> 3), kl = (t & 7) * 8;
    f16x8 r;
#pragma unroll
    for (int j = 0; j < 8; ++j) r[j] = sT[kl + j][nl];
    *reinterpret_cast<f16x8*>(wT + (size_t)(n0 + nl) * 512 + k0 + kl) = r;
  }
}

// WcT[j][k'] with k' = h*64 + half*32 + d  (matches k_attn's cat col order).
__global__ __launch_bounds__(256) void k_compose(const float* __restrict__ lpw,
                                                 const float* __restrict__ gpw,
                                                 const float* __restrict__ pfc_w,
                                                 f16* __restrict__ WT) {
  __shared__ float sW[16][16];
  const int kk0 = blockIdx.x * 16;
  const bool top = kk0 < 512;
  const float* src = top ? (lpw + kk0 * 512) : (gpw + (kk0 - 512) * 512);
  const float* pf = pfc_w + (top ? 0 : 512 * 512);
  const int t = threadIdx.x;
  float acc0[16], acc1[16];
#pragma unroll
  for (int i = 0; i < 16; ++i) { acc0[i] = 0.f; acc1[i] = 0.f; }
  for (int ct = 0; ct < 32; ++ct) {
    sW[t >> 4][t & 15] = src[(t >> 4) * 512 + ct * 16 + (t & 15)];
    __syncthreads();
#pragma unroll
    for (int cc = 0; cc < 16; ++cc) {
      const int c = ct * 16 + cc;
      const float p0 = pf[c * 512 + t];
      const float p1 = pf[c * 512 + t + 256];
#pragma unroll
      for (int i = 0; i < 16; ++i) { acc0[i] += sW[i][cc] * p0; acc1[i] += sW[i][cc] * p1; }
    }
    __syncthreads();
  }
#pragma unroll
  for (int i = 0; i < 16; ++i) {
    const int kk = kk0 + i;
    const int kp = ((kk >> 5) & 15) * 64 + (kk >> 9) * 32 + (kk & 31);
    WT[(size_t)t * 1024 + kp] = (f16)acc0[i];
    WT[(size_t)(t + 256) * 1024 + kp] = (f16)acc1[i];
  }
}

__global__ void k_bc_init(const float* __restrict__ pfc_b, float* __restrict__ bc) {
  const int j = blockIdx.x * 256 + threadIdx.x;
  bc[j] = pfc_b[j];
}

__global__ void k_bc_acc(const float* __restrict__ lpb, const float* __restrict__ gpb,
                         const float* __restrict__ pfc_w, float* __restrict__ bc) {
  const int t = threadIdx.x;
  const int c0 = blockIdx.x * 32;
  float p0 = 0.f, p1 = 0.f;
#pragma unroll
  for (int i = 0; i < 32; ++i) {
    const int c = c0 + i;
    const float wgt = (c < 512) ? lpb[c] : gpb[c - 512];
    p0 += wgt * pfc_w[(size_t)c * 512 + t];
    p1 += wgt * pfc_w[(size_t)c * 512 + t + 256];
  }
  atomicAdd(bc + t, p0);
  atomicAdd(bc + t + 256, p1);
}

// ---------------------------------------------------------------------------
// QKV GEMM + fused pooling (unchanged from round 4).
// ---------------------------------------------------------------------------
__global__ __launch_bounds__(512, 2) void k_gemm_qkv(const float* __restrict__ X,
                                                     const f16* __restrict__ BT,
                                                     const float* __restrict__ qkv_b,
                                                     const float* __restrict__ pool_w,
                                                     const float* __restrict__ pool_b,
                                                     f16* __restrict__ qb,
                                                     f16* __restrict__ kb,
                                                     f16* __restrict__ vb,
                                                     f16* __restrict__ Kgb,
                                                     f16* __restrict__ Vgt) {
  __shared__ float sA[8192];
  __shared__ f16 sB[4096];
  const int wid = (blockIdx.x & 7) * 384 + (blockIdx.x >> 3);
  const int br = wid / 12, bn = wid % 12;
  const int t = threadIdx.x;
  const int wv = t >> 6, l = t & 63, lr = l & 15, lk = l >> 4;
  const int wvr = wv >> 1, wvc = wv & 1;

  f32x4 acc[4][4] = {};

  const int arow = t >> 3;
  const int afc = ((t & 7) ^ (arow & 7)) * 4;
  const float* gA = X + (size_t)(br * 256 + arow) * 512 + afc;
  const int brow = t >> 2;
  const int bfc = ((t & 3) ^ (brow & 3)) * 8;
  const f16* gB = BT + (size_t)(bn * 128 + brow) * 512 + bfc;

  for (int kk = 0; kk < 16; ++kk) {
#pragma unroll
    for (int i = 0; i < 4; ++i)
      async_cp16(gA + (size_t)(i * 64) * 512 + kk * 32, &sA[(i * 512 + t) * 4]);
    async_cp16(gB + kk * 32, &sB[t * 8]);
    __syncthreads();
    f16x8 af[4], bf[4];
#pragma unroll
    for (int m = 0; m < 4; ++m) {
      const int row = wvr * 64 + m * 16 + lr;
      const int c0 = (2 * lk) ^ (lr & 7), c1 = (2 * lk + 1) ^ (lr & 7);
      const float4 v0 = *reinterpret_cast<const float4*>(&sA[row * 32 + c0 * 4]);
      const float4 v1 = *reinterpret_cast<const float4*>(&sA[row * 32 + c1 * 4]);
      af[m] = cvt8_rtz(v0, v1);
    }
#pragma unroll
    for (int n = 0; n < 4; ++n) {
      const int row = wvc * 64 + n * 16 + lr;
      bf[n] = *reinterpret_cast<const f16x8*>(&sB[row * 32 + ((lk ^ (lr & 3)) * 8)]);
    }
#pragma unroll
    for (int m = 0; m < 4; ++m)
#pragma unroll
      for (int n = 0; n < 4; ++n) acc[m][n] = mfma_16x16x32(af[m], bf[n], acc[m][n]);
    __syncthreads();
  }

  const int w_idx = br * 4 + wvr;
  const int bb = w_idx >> 6, ww = w_idx & 63;
  float pw[4][4];
#pragma unroll
  for (int m = 0; m < 4; ++m)
#pragma unroll
    for (int r = 0; r < 4; ++r) pw[m][r] = pool_w[m * 16 + lk * 4 + r];
  const float pb = pool_b[0];

#pragma unroll
  for (int n = 0; n < 4; ++n) {
    const int col = bn * 128 + wvc * 64 + n * 16 + lr;
    const int which = col >> 9;
    const int hh = (col >> 5) & 15, d = col & 31;
    const float bias = qkv_b[col];
    f16* dst = which == 0 ? qb : (which == 1 ? kb : vb);
#pragma unroll
    for (int m = 0; m < 4; ++m)
#pragma unroll
      for (int r = 0; r < 4; ++r) {
        const int row = br * 256 + wvr * 64 + m * 16 + lk * 4 + r;
        dst[(size_t)(((row >> 6) << 4) + hh) * 2048 + (row & 63) * 32 + d] =
            (f16)(acc[m][n][r] + bias);
      }
    if (which != 0) {
      float part = 0.f;
#pragma unroll
      for (int m = 0; m < 4; ++m)
#pragma unroll
        for (int r = 0; r < 4; ++r) part += (acc[m][n][r] + bias) * pw[m][r];
      part += __shfl_xor(part, 16);
      part += __shfl_xor(part, 32);
      part += pb;
      if (lk == 0) {
        if (which == 1)
          Kgb[((size_t)(bb * 16 + hh) * 64 + ww) * 32 + d] = (f16)part;
        else
          Vgt[((size_t)(bb * 16 + hh) * 32 + d) * 64 + ww] = (f16)part;
      }
    }
  }
}

// ---------------------------------------------------------------------------
// Attention. One block per (b_, h): 4 waves x 16 q-rows. 2 barriers.
// Q/K/Kg frags from global (coalesced, L2). V transposed in LDS (swizzled).
// cat cols permuted: block writes cat[., h*64 + half*32 + d] (contiguous 128B/row).
// ---------------------------------------------------------------------------
__global__ __launch_bounds__(256) void k_attn(const f16* __restrict__ qb,
                                              const f16* __restrict__ kb,
                                              const f16* __restrict__ vb,
                                              const f16* __restrict__ Kgb,
                                              const f16* __restrict__ Vgt,
                                              const float* __restrict__ lbf,
                                              const float* __restrict__ gbf,
                                              f16* __restrict__ cat) {
  __shared__ f16 sVraw[2048];  // [64 tok][32 d]
  __shared__ f16 sVt[2048];    // [32 d][8 chunks x 8 tok], chunk ^= d&7
  __shared__ f16 sP[4096];     // [64 rows][8 chunks x 8],  chunk ^= row&7
  __shared__ f16 sCat[4096];   // [64 rows][8 chunks x 8],  chunk ^= row&7
  const int bid = blockIdx.x;          // b_*16 + h
  const int b_ = bid >> 4, h = bid & 15;
  const int gs = ((b_ >> 6) << 4) + h; // b*16 + h
  const int t = threadIdx.x;
  const int wv = t >> 6, l = t & 63, lr = l & 15, lk = l >> 4;
  const float scale = 0.17677669529663687f;
  const size_t hs = (size_t)bid * 2048;

  async_cp16(vb + hs + t * 8, &sVraw[t * 8]);

  const f16x8 aq = *reinterpret_cast<const f16x8*>(qb + hs + (wv * 16 + lr) * 32 + lk * 8);

  // ---- fine QK^T (K from global) ----
  f32x4 s[4];
#pragma unroll
  for (int j = 0; j < 4; ++j) {
    const f16x8 bk = *reinterpret_cast<const f16x8*>(kb + hs + (j * 16 + lr) * 32 + lk * 8);
    f32x4 z = {};
    s[j] = mfma_16x16x32(aq, bk, z);
  }

  __syncthreads();   // sVraw staged

  // transpose V -> sVt (swizzled)
  {
    const int d = t >> 3, tok0 = (t & 7) << 3;
    f16x8 w;
#pragma unroll
    for (int j = 0; j < 8; ++j) w[j] = sVraw[(tok0 + j) * 32 + d];
    *reinterpret_cast<f16x8*>(&sVt[d * 64 + (((t & 7) ^ (d & 7)) << 3)]) = w;
  }

  // fine softmax -> sP (wave-private rows)
  float p[4][4], inv[4];
  {
    const float* bt = lbf + h * 4096 + (wv * 16 + lk * 4) * 64;
#pragma unroll
    for (int r = 0; r < 4; ++r) {
      float m = -1e30f;
#pragma unroll
      for (int j = 0; j < 4; ++j) {
        const float v = s[j][r] * scale + bt[r * 64 + j * 16 + lr];
        p[j][r] = v;
        m = fmaxf(m, v);
      }
      m = fmaxf(m, __shfl_xor(m, 1));
      m = fmaxf(m, __shfl_xor(m, 2));
      m = fmaxf(m, __shfl_xor(m, 4));
      m = fmaxf(m, __shfl_xor(m, 8));
      float su = 0.f;
#pragma unroll
      for (int j = 0; j < 4; ++j) {
        const float e = __expf(p[j][r] - m);
        p[j][r] = e;
        su += e;
      }
      su += __shfl_xor(su, 1);
      su += __shfl_xor(su, 2);
      su += __shfl_xor(su, 4);
      su += __shfl_xor(su, 8);
      inv[r] = 1.f / su;
    }
#pragma unroll
    for (int r = 0; r < 4; ++r) {
      const int rowP = wv * 16 + lk * 4 + r;
#pragma unroll
      for (int j = 0; j < 4; ++j) {
        const int col = j * 16 + lr;
        sP[rowP * 64 + (((col >> 3) ^ (rowP & 7)) << 3) + (col & 7)] = (f16)p[j][r];
      }
    }
  }

  __syncthreads();   // sVt ready

  // ---- fine PV -> sCat cols 0..31 ----
  {
    const int rowP = wv * 16 + lr;
    const f16x8 a0 = *reinterpret_cast<const f16x8*>(&sP[rowP * 64 + ((lk ^ (lr & 7)) << 3)]);
    const f16x8 a1 = *reinterpret_cast<const f16x8*>(&sP[rowP * 64 + (((4 + lk) ^ (lr & 7)) << 3)]);
#pragma unroll
    for (int n = 0; n < 2; ++n) {
      const int d = n * 16 + lr;
      const f16x8 b0 = *reinterpret_cast<const f16x8*>(&sVt[d * 64 + ((lk ^ (d & 7)) << 3)]);
      const f16x8 b1 = *reinterpret_cast<const f16x8*>(&sVt[d * 64 + (((4 + lk) ^ (d & 7)) << 3)]);
      f32x4 o = {};
      o = mfma_16x16x32(a0, b0, o);
      o = mfma_16x16x32(a1, b1, o);
#pragma unroll
      for (int r = 0; r < 4; ++r) {
        const int rowC = wv * 16 + lk * 4 + r;
        const int colC = n * 16 + lr;
        sCat[rowC * 64 + (((colC >> 3) ^ (rowC & 7)) << 3) + (colC & 7)] =
            (f16)(o[r] * inv[r]);
      }
    }
  }

  // ---- coarse QK^T (Kg from global) ----
#pragma unroll
  for (int j = 0; j < 4; ++j) {
    const f16x8 bk = *reinterpret_cast<const f16x8*>(
        Kgb + ((size_t)gs * 64 + j * 16 + lr) * 32 + lk * 8);
    f32x4 z = {};
    s[j] = mfma_16x16x32(aq, bk, z);
  }
  {
    const float* bt = gbf + h * 4096 + (wv * 16 + lk * 4) * 64;
#pragma unroll
    for (int r = 0; r < 4; ++r) {
      float m = -1e30f;
#pragma unroll
      for (int j = 0; j < 4; ++j) {
        const float v = s[j][r] * scale + bt[r * 64 + j * 16 + lr];
        p[j][r] = v;
        m = fmaxf(m, v);
      }
      m = fmaxf(m, __shfl_xor(m, 1));
      m = fmaxf(m, __shfl_xor(m, 2));
      m = fmaxf(m, __shfl_xor(m, 4));
      m = fmaxf(m, __shfl_xor(m, 8));
      float su = 0.f;
#pragma unroll
      for (int j = 0; j < 4; ++j) {
        const float e = __expf(p[j][r] - m);
        p[j][r] = e;
        su += e;
      }
      su += __shfl_xor(su, 1);
      su += __shfl_xor(su, 2);
      su += __shfl_xor(su, 4);
      su += __shfl_xor(su, 8);
      inv[r] = 1.f / su;
    }
    // overwrite same wave-private sP rows (in-order DS per wave; fine PV already read)
#pragma unroll
    for (int r = 0; r < 4; ++r) {
      const int rowP = wv * 16 + lk * 4 + r;
#pragma unroll
      for (int j = 0; j < 4; ++j) {
        const int col = j * 16 + lr;
        sP[rowP * 64 + (((col >> 3) ^ (rowP & 7)) << 3) + (col & 7)] = (f16)p[j][r];
      }
    }
  }

  // ---- coarse PV (Vg from global, already transposed) -> sCat cols 32..63 ----
  {
    const int rowP = wv * 16 + lr;
    const f16x8 a0 = *reinterpret_cast<const f16x8*>(&sP[rowP * 64 + ((lk ^ (lr & 7)) << 3)]);
    const f16x8 a1 = *reinterpret_cast<const f16x8*>(&sP[rowP * 64 + (((4 + lk) ^ (lr & 7)) << 3)]);
#pragma unroll
    for (int n = 0; n < 2; ++n) {
      const f16* vp = Vgt + ((size_t)gs * 32 + n * 16 + lr) * 64 + lk * 8;
      const f16x8 b0 = *reinterpret_cast<const f16x8*>(vp);
      const f16x8 b1 = *reinterpret_cast<const f16x8*>(vp + 32);
      f32x4 o = {};
      o = mfma_16x16x32(a0, b0, o);
      o = mfma_16x16x32(a1, b1, o);
#pragma unroll
      for (int r = 0; r < 4; ++r) {
        const int rowC = wv * 16 + lk * 4 + r;
        const int colC = 32 + n * 16 + lr;
        sCat[rowC * 64 + (((colC >> 3) ^ (rowC & 7)) << 3) + (colC & 7)] =
            (f16)(o[r] * inv[r]);
      }
    }
  }

  // ---- store sCat (wave-private rows) -> cat, vectorized ----
  f16* catp = cat + ((size_t)b_ * 64) * 1024 + h * 64;
#pragma unroll
  for (int pass = 0; pass < 2; ++pass) {
    const int row = wv * 16 + pass * 8 + (l >> 3);
    const int c = l & 7;
    const f16x8 v = *reinterpret_cast<const f16x8*>(&sCat[row * 64 + ((c ^ (row & 7)) << 3)]);
    *reinterpret_cast<f16x8*>(catp + (size_t)row * 1024 + c * 8) = v;
  }
}

// ---------------------------------------------------------------------------
// Final GEMM: out(65536x512 fp32) = cat @ WcT^T + bc. 256x128 tile, BK=64,
// 8 waves, 8-chunk XOR (conflict-free), XCD-chunked swizzle. grid 1024 x 512.
// ---------------------------------------------------------------------------
__global__ __launch_bounds__(512) void k_gemm_final(const f16* __restrict__ A,
                                                    const f16* __restrict__ BT,
                                                    const float* __restrict__ bc,
                                                    float* __restrict__ out) {
  __shared__ f16 sA[16384];   // [256 rows][8 chunks x 8], chunk ^= row&7
  __shared__ f16 sB[8192];    // [128 rows][8 chunks x 8], chunk ^= row&7
  const int wid = (blockIdx.x & 7) * 128 + (blockIdx.x >> 3);
  const int br = wid >> 2, bn = wid & 3;
  const int t = threadIdx.x;
  const int wv = t >> 6, l = t & 63, lr = l & 15, lk = l >> 4;
  const int wvr = wv >> 1, wvc = wv & 1;

  f32x4 acc[4][4] = {};

  const int srow = t >> 3;                      // 0..63 (+i*64)
  const int sch = ((t & 7) ^ (srow & 7)) * 8;   // swizzled chunk offset (f16)
  const f16* gA = A + (size_t)(br * 256 + srow) * 1024 + sch;
  const f16* gB = BT + (size_t)(bn * 128 + srow) * 1024 + sch;

  for (int kk = 0; kk < 16; ++kk) {
#pragma unroll
    for (int i = 0; i < 4; ++i)
      async_cp16(gA + (size_t)(i * 64) * 1024 + kk * 64, &sA[(i * 512 + t) * 8]);
#pragma unroll
    for (int i = 0; i < 2; ++i)
      async_cp16(gB + (size_t)(i * 64) * 1024 + kk * 64, &sB[(i * 512 + t) * 8]);
    __syncthreads();
    f16x8 af[4][2], bf[4][2];
#pragma unroll
    for (int m = 0; m < 4; ++m) {
      const int row = wvr * 64 + m * 16 + lr;
#pragma unroll
      for (int ks = 0; ks < 2; ++ks)
        af[m][ks] = *reinterpret_cast<const f16x8*>(
            &sA[row * 64 + (((ks * 4 + lk) ^ (row & 7)) << 3)]);
    }
#pragma unroll
    for (int n = 0; n < 4; ++n) {
      const int row = wvc * 64 + n * 16 + lr;
#pragma unroll
      for (int ks = 0; ks < 2; ++ks)
        bf[n][ks] = *reinterpret_cast<const f16x8*>(
            &sB[row * 64 + (((ks * 4 + lk) ^ (row & 7)) << 3)]);
    }
#pragma unroll
    for (int m = 0; m < 4; ++m)
#pragma unroll
      for (int n = 0; n < 4; ++n) {
        acc[m][n] = mfma_16x16x32(af[m][0], bf[n][0], acc[m][n]);
        acc[m][n] = mfma_16x16x32(af[m][1], bf[n][1], acc[m][n]);
      }
    __syncthreads();
  }

#pragma unroll
  for (int n = 0; n < 4; ++n) {
    const int col = bn * 128 + wvc * 64 + n * 16 + lr;
    const float bias = bc[col];
#pragma unroll
    for (int m = 0; m < 4; ++m)
#pragma unroll
      for (int r = 0; r < 4; ++r) {
        const int row = br * 256 + wvr * 64 + m * 16 + lk * 4 + r;
        out[(size_t)row * 512 + col] = acc[m][n][r] + bias;
      }
  }
}

// ---------------------------------------------------------------------------

extern "C" void kernel_launch(void* const* d_in, const int* in_sizes, int n_in,
                              void* d_out, int out_size, void* d_ws, size_t ws_size,
                              hipStream_t stream) {
  const float* x      = (const float*)d_in[0];
  const float* qkv_w  = (const float*)d_in[1];
  const float* qkv_b  = (const float*)d_in[2];
  const float* ltab   = (const float*)d_in[3];
  const float* gtab   = (const float*)d_in[4];
  const float* lpw    = (const float*)d_in[5];
  const float* lpb    = (const float*)d_in[6];
  const float* pool_w = (const float*)d_in[7];
  const float* pool_b = (const float*)d_in[8];
  const float* gpw    = (const float*)d_in[9];
  const float* gpb    = (const float*)d_in[10];
  const float* pfc_w  = (const float*)d_in[11];
  const float* pfc_b  = (const float*)d_in[12];
  float* out = (float*)d_out;

  char* ws = (char*)d_ws;
  f16*   qb   = (f16*)(ws + 0);
  f16*   kb   = (f16*)(ws + 67108864);
  f16*   vb   = (f16*)(ws + 134217728);
  f16*   cat  = (f16*)(ws + 201326592);
  f16*   qwT  = (f16*)(ws + 335544320);
  f16*   WcT  = (f16*)(ws + 337117184);
  float* bc   = (float*)(ws + 338165760);
  float* lbf  = (float*)(ws + 338167808);
  float* gbf  = (float*)(ws + 338429952);
  f16*   Kgb  = (f16*)(ws + 338692096);
  f16*   Vgt  = (f16*)(ws + 339740672);

  k_biastab<<<32, 256, 0, stream>>>(ltab, gtab, lbf, gbf);
  k_tqkvw<<<192, 256, 0, stream>>>(qkv_w, qwT);
  k_compose<<<64, 256, 0, stream>>>(lpw, gpw, pfc_w, WcT);
  k_bc_init<<<2, 256, 0, stream>>>(pfc_b, bc);
  k_bc_acc<<<32, 256, 0, stream>>>(lpb, gpb, pfc_w, bc);
  k_gemm_qkv<<<3072, 512, 0, stream>>>(x, qwT, qkv_b, pool_w, pool_b,
                                       qb, kb, vb, Kgb, Vgt);
  k_attn<<<16384, 256, 0, stream>>>(qb, kb, vb, Kgb, Vgt, lbf, gbf, cat);
  k_gemm_final<<<1024, 512, 0, stream>>>(cat, WcT, bc, out);
}

// Round 6
// 542.503 us; speedup vs baseline: 1.6559x; 1.0063x over previous
//
#include <hip/hip_runtime.h>

// PFCAttention on MI355X (gfx950). Round 6.
// B=16, H=W=64, C=512, WS=8 -> N=64 tok/window, nWs=64, B_=1024, NH=16, hd=32.
//
// Round-6 change (single focus): k_gemm_qkv A-path reg-staged —
//   global fp32 -> VGPR -> cvt_pkrtz once -> fp16 LDS (ds_write_b128).
//   Inner loop identical to round-2's fp16 path (which ran 145 us), but
//   without the cvtx kernel's 402 MB round trip. A-loads for step kk+1
//   issued right after barrier 1 (latency hidden under MFMA).
// k_attn / k_gemm_final / prep unchanged from round 5.
//
// Workspace (bytes):
//   qb 0 / kb 67108864 / vb 134217728 (64 MiB each, fp16 [B_*NH][64][32])
//   cat 201326592 (128 MiB fp16 [65536][1024], cols h*64+half*32+d)
//   qwT 335544320 (1.5 MiB) WcT 337117184 (1 MiB) bc 338165760 (2 KiB)
//   lbf 338167808 / gbf 338429952 (256 KiB each)
//   Kgb 338692096 (1 MiB [B*NH][64][32])  Vgt 339740672 (1 MiB [B*NH][32][64])

typedef unsigned int u32;
typedef _Float16 f16;
typedef __attribute__((ext_vector_type(8))) _Float16 f16x8;
typedef __attribute__((ext_vector_type(4))) float f32x4;
typedef __attribute__((ext_vector_type(4))) u32 u32x4;

__device__ __forceinline__ f32x4 mfma_16x16x32(f16x8 a, f16x8 b, f32x4 c) {
  return __builtin_amdgcn_mfma_f32_16x16x32_f16(a, b, c, 0, 0, 0);
}

__device__ __forceinline__ void async_cp16(const void* g, void* l) {
  __builtin_amdgcn_global_load_lds(
      (const __attribute__((address_space(1))) u32*)g,
      (__attribute__((address_space(3))) u32*)l, 16, 0, 0);
}

__device__ __forceinline__ f16x8 cvt8_rtz(const float4 a, const float4 b) {
  u32x4 w;
  w[0] = __builtin_bit_cast(u32, __builtin_amdgcn_cvt_pkrtz(a.x, a.y));
  w[1] = __builtin_bit_cast(u32, __builtin_amdgcn_cvt_pkrtz(a.z, a.w));
  w[2] = __builtin_bit_cast(u32, __builtin_amdgcn_cvt_pkrtz(b.x, b.y));
  w[3] = __builtin_bit_cast(u32, __builtin_amdgcn_cvt_pkrtz(b.z, b.w));
  return __builtin_bit_cast(f16x8, w);
}

// ---------------------------------------------------------------------------
// Prep kernels (unchanged)
// ---------------------------------------------------------------------------

__global__ void k_biastab(const float* __restrict__ ltab, const float* __restrict__ gtab,
                          float* __restrict__ lbf, float* __restrict__ gbf) {
  const int id = blockIdx.x * 256 + threadIdx.x;   // 0..8191
  const int pair = id & 4095;
  const int n = pair >> 6, m = pair & 63;
  const int yn = n >> 3, xn = n & 7;
  const int ym = m >> 3, xm = m & 7;
  const int idx = (yn - ym + 7) * 15 + (xn - xm + 7);
  if (id < 4096) {
#pragma unroll
    for (int h = 0; h < 16; ++h) lbf[h * 4096 + pair] = ltab[idx * 16 + h];
  } else {
#pragma unroll
    for (int h = 0; h < 16; ++h) gbf[h * 4096 + pair] = gtab[idx * 16 + h];
  }
}

__global__ void k_tqkvw(const float* __restrict__ w, f16* __restrict__ wT) {
  __shared__ f16 sT[64][72];
  const int bid = blockIdx.x;
  const int k0 = (bid / 24) * 64, n0 = (bid % 24) * 64;
  const int t = threadIdx.x;
#pragma unroll
  for (int p = 0; p < 4; ++p) {
    const int kl = p * 16 + (t >> 4), nl = (t & 15) * 4;
    const float4 v = *reinterpret_cast<const float4*>(w + (size_t)(k0 + kl) * 1536 + n0 + nl);
    sT[kl][nl] = (f16)v.x; sT[kl][nl + 1] = (f16)v.y;
    sT[kl][nl + 2] = (f16)v.z; sT[kl][nl + 3] = (f16)v.w;
  }
  __syncthreads();
#pragma unroll
  for (int q = 0; q < 2; ++q) {
    const int nl = q * 32 + (t >> 3), kl = (t & 7) * 8;
    f16x8 r;
#pragma unroll
    for (int j = 0; j < 8; ++j) r[j] = sT[kl + j][nl];
    *reinterpret_cast<f16x8*>(wT + (size_t)(n0 + nl) * 512 + k0 + kl) = r;
  }
}

// WcT[j][k'] with k' = h*64 + half*32 + d  (matches k_attn's cat col order).
__global__ __launch_bounds__(256) void k_compose(const float* __restrict__ lpw,
                                                 const float* __restrict__ gpw,
                                                 const float* __restrict__ pfc_w,
                                                 f16* __restrict__ WT) {
  __shared__ float sW[16][16];
  const int kk0 = blockIdx.x * 16;
  const bool top = kk0 < 512;
  const float* src = top ? (lpw + kk0 * 512) : (gpw + (kk0 - 512) * 512);
  const float* pf = pfc_w + (top ? 0 : 512 * 512);
  const int t = threadIdx.x;
  float acc0[16], acc1[16];
#pragma unroll
  for (int i = 0; i < 16; ++i) { acc0[i] = 0.f; acc1[i] = 0.f; }
  for (int ct = 0; ct < 32; ++ct) {
    sW[t >> 4][t & 15] = src[(t >> 4) * 512 + ct * 16 + (t & 15)];
    __syncthreads();
#pragma unroll
    for (int cc = 0; cc < 16; ++cc) {
      const int c = ct * 16 + cc;
      const float p0 = pf[c * 512 + t];
      const float p1 = pf[c * 512 + t + 256];
#pragma unroll
      for (int i = 0; i < 16; ++i) { acc0[i] += sW[i][cc] * p0; acc1[i] += sW[i][cc] * p1; }
    }
    __syncthreads();
  }
#pragma unroll
  for (int i = 0; i < 16; ++i) {
    const int kk = kk0 + i;
    const int kp = ((kk >> 5) & 15) * 64 + (kk >> 9) * 32 + (kk & 31);
    WT[(size_t)t * 1024 + kp] = (f16)acc0[i];
    WT[(size_t)(t + 256) * 1024 + kp] = (f16)acc1[i];
  }
}

__global__ void k_bc_init(const float* __restrict__ pfc_b, float* __restrict__ bc) {
  const int j = blockIdx.x * 256 + threadIdx.x;
  bc[j] = pfc_b[j];
}

__global__ void k_bc_acc(const float* __restrict__ lpb, const float* __restrict__ gpb,
                         const float* __restrict__ pfc_w, float* __restrict__ bc) {
  const int t = threadIdx.x;
  const int c0 = blockIdx.x * 32;
  float p0 = 0.f, p1 = 0.f;
#pragma unroll
  for (int i = 0; i < 32; ++i) {
    const int c = c0 + i;
    const float wgt = (c < 512) ? lpb[c] : gpb[c - 512];
    p0 += wgt * pfc_w[(size_t)c * 512 + t];
    p1 += wgt * pfc_w[(size_t)c * 512 + t + 256];
  }
  atomicAdd(bc + t, p0);
  atomicAdd(bc + t + 256, p1);
}

// ---------------------------------------------------------------------------
// QKV GEMM + fused pooling. A: fp32 global -> VGPR -> cvt once -> fp16 LDS.
// 256x128 tile, 8 waves (4r x 2c), K-step 32, XCD-chunked swizzle. grid 3072 x 512.
// ---------------------------------------------------------------------------
__global__ __launch_bounds__(512, 2) void k_gemm_qkv(const float* __restrict__ X,
                                                     const f16* __restrict__ BT,
                                                     const float* __restrict__ qkv_b,
                                                     const float* __restrict__ pool_w,
                                                     const float* __restrict__ pool_b,
                                                     f16* __restrict__ qb,
                                                     f16* __restrict__ kb,
                                                     f16* __restrict__ vb,
                                                     f16* __restrict__ Kgb,
                                                     f16* __restrict__ Vgt) {
  __shared__ f16 sA[8192];   // [256 rows][4 chunks x 8 f16], chunk ^= row&3
  __shared__ f16 sB[4096];   // [128 rows][4 chunks x 8 f16], chunk ^= row&3
  const int wid = (blockIdx.x & 7) * 384 + (blockIdx.x >> 3);
  const int br = wid / 12, bn = wid % 12;
  const int t = threadIdx.x;
  const int wv = t >> 6, l = t & 63, lr = l & 15, lk = l >> 4;
  const int wvr = wv >> 1, wvc = wv & 1;

  f32x4 acc[4][4] = {};

  // A reg-staging: thread t owns row (t>>1), chunks {2(t&1), 2(t&1)+1}
  const int arow = t >> 1;
  const int ac0 = (t & 1) * 2;
  const float* gA = X + (size_t)(br * 256 + arow) * 512 + ac0 * 8;
  const int aslot0 = (ac0 ^ (arow & 3)) * 8;
  const int aslot1 = ((ac0 + 1) ^ (arow & 3)) * 8;
  // B staging via global_load_lds (pre-swizzled source)
  const int brow = t >> 2;
  const int bfc = ((t & 3) ^ (brow & 3)) * 8;
  const f16* gB = BT + (size_t)(bn * 128 + brow) * 512 + bfc;

  float4 ar0, ar1, ar2, ar3;
  {
    ar0 = *reinterpret_cast<const float4*>(gA);
    ar1 = *reinterpret_cast<const float4*>(gA + 4);
    ar2 = *reinterpret_cast<const float4*>(gA + 8);
    ar3 = *reinterpret_cast<const float4*>(gA + 12);
  }

  for (int kk = 0; kk < 16; ++kk) {
    // LDS is free here (post-barrier of previous step)
    *reinterpret_cast<f16x8*>(&sA[arow * 32 + aslot0]) = cvt8_rtz(ar0, ar1);
    *reinterpret_cast<f16x8*>(&sA[arow * 32 + aslot1]) = cvt8_rtz(ar2, ar3);
    async_cp16(gB + kk * 32, &sB[t * 8]);
    __syncthreads();   // A written, B landed
    if (kk < 15) {     // prefetch next A-tile into regs (hidden under MFMA)
      const float* g = gA + (kk + 1) * 32;
      ar0 = *reinterpret_cast<const float4*>(g);
      ar1 = *reinterpret_cast<const float4*>(g + 4);
      ar2 = *reinterpret_cast<const float4*>(g + 8);
      ar3 = *reinterpret_cast<const float4*>(g + 12);
    }
    f16x8 af[4], bf[4];
#pragma unroll
    for (int m = 0; m < 4; ++m) {
      const int row = wvr * 64 + m * 16 + lr;
      af[m] = *reinterpret_cast<const f16x8*>(&sA[row * 32 + ((lk ^ (lr & 3)) * 8)]);
    }
#pragma unroll
    for (int n = 0; n < 4; ++n) {
      const int row = wvc * 64 + n * 16 + lr;
      bf[n] = *reinterpret_cast<const f16x8*>(&sB[row * 32 + ((lk ^ (lr & 3)) * 8)]);
    }
#pragma unroll
    for (int m = 0; m < 4; ++m)
#pragma unroll
      for (int n = 0; n < 4; ++n) acc[m][n] = mfma_16x16x32(af[m], bf[n], acc[m][n]);
    __syncthreads();
  }

  // epilogue: scatter q/k/v + fused pooling (wave's 64 rows = one window)
  const int w_idx = br * 4 + wvr;
  const int bb = w_idx >> 6, ww = w_idx & 63;
  float pw[4][4];
#pragma unroll
  for (int m = 0; m < 4; ++m)
#pragma unroll
    for (int r = 0; r < 4; ++r) pw[m][r] = pool_w[m * 16 + lk * 4 + r];
  const float pb = pool_b[0];

#pragma unroll
  for (int n = 0; n < 4; ++n) {
    const int col = bn * 128 + wvc * 64 + n * 16 + lr;   // 0..1535
    const int which = col >> 9;
    const int hh = (col >> 5) & 15, d = col & 31;
    const float bias = qkv_b[col];
    f16* dst = which == 0 ? qb : (which == 1 ? kb : vb);
#pragma unroll
    for (int m = 0; m < 4; ++m)
#pragma unroll
      for (int r = 0; r < 4; ++r) {
        const int row = br * 256 + wvr * 64 + m * 16 + lk * 4 + r;
        dst[(size_t)(((row >> 6) << 4) + hh) * 2048 + (row & 63) * 32 + d] =
            (f16)(acc[m][n][r] + bias);
      }
    if (which != 0) {
      float part = 0.f;
#pragma unroll
      for (int m = 0; m < 4; ++m)
#pragma unroll
        for (int r = 0; r < 4; ++r) part += (acc[m][n][r] + bias) * pw[m][r];
      part += __shfl_xor(part, 16);
      part += __shfl_xor(part, 32);
      part += pb;
      if (lk == 0) {
        if (which == 1)
          Kgb[((size_t)(bb * 16 + hh) * 64 + ww) * 32 + d] = (f16)part;
        else
          Vgt[((size_t)(bb * 16 + hh) * 32 + d) * 64 + ww] = (f16)part;
      }
    }
  }
}

// ---------------------------------------------------------------------------
// Attention (unchanged from round 5). One block per (b_, h): 4 waves, 2 barriers.
// ---------------------------------------------------------------------------
__global__ __launch_bounds__(256) void k_attn(const f16* __restrict__ qb,
                                              const f16* __restrict__ kb,
                                              const f16* __restrict__ vb,
                                              const f16* __restrict__ Kgb,
                                              const f16* __restrict__ Vgt,
                                              const float* __restrict__ lbf,
                                              const float* __restrict__ gbf,
                                              f16* __restrict__ cat) {
  __shared__ f16 sVraw[2048];  // [64 tok][32 d]
  __shared__ f16 sVt[2048];    // [32 d][8 chunks x 8 tok], chunk ^= d&7
  __shared__ f16 sP[4096];     // [64 rows][8 chunks x 8],  chunk ^= row&7
  __shared__ f16 sCat[4096];   // [64 rows][8 chunks x 8],  chunk ^= row&7
  const int bid = blockIdx.x;          // b_*16 + h
  const int b_ = bid >> 4, h = bid & 15;
  const int gs = ((b_ >> 6) << 4) + h; // b*16 + h
  const int t = threadIdx.x;
  const int wv = t >> 6, l = t & 63, lr = l & 15, lk = l >> 4;
  const float scale = 0.17677669529663687f;
  const size_t hs = (size_t)bid * 2048;

  async_cp16(vb + hs + t * 8, &sVraw[t * 8]);

  const f16x8 aq = *reinterpret_cast<const f16x8*>(qb + hs + (wv * 16 + lr) * 32 + lk * 8);

  // ---- fine QK^T (K from global) ----
  f32x4 s[4];
#pragma unroll
  for (int j = 0; j < 4; ++j) {
    const f16x8 bk = *reinterpret_cast<const f16x8*>(kb + hs + (j * 16 + lr) * 32 + lk * 8);
    f32x4 z = {};
    s[j] = mfma_16x16x32(aq, bk, z);
  }

  __syncthreads();   // sVraw staged

  // transpose V -> sVt (swizzled)
  {
    const int d = t >> 3, tok0 = (t & 7) << 3;
    f16x8 w;
#pragma unroll
    for (int j = 0; j < 8; ++j) w[j] = sVraw[(tok0 + j) * 32 + d];
    *reinterpret_cast<f16x8*>(&sVt[d * 64 + (((t & 7) ^ (d & 7)) << 3)]) = w;
  }

  // fine softmax -> sP (wave-private rows)
  float p[4][4], inv[4];
  {
    const float* bt = lbf + h * 4096 + (wv * 16 + lk * 4) * 64;
#pragma unroll
    for (int r = 0; r < 4; ++r) {
      float m = -1e30f;
#pragma unroll
      for (int j = 0; j < 4; ++j) {
        const float v = s[j][r] * scale + bt[r * 64 + j * 16 + lr];
        p[j][r] = v;
        m = fmaxf(m, v);
      }
      m = fmaxf(m, __shfl_xor(m, 1));
      m = fmaxf(m, __shfl_xor(m, 2));
      m = fmaxf(m, __shfl_xor(m, 4));
      m = fmaxf(m, __shfl_xor(m, 8));
      float su = 0.f;
#pragma unroll
      for (int j = 0; j < 4; ++j) {
        const float e = __expf(p[j][r] - m);
        p[j][r] = e;
        su += e;
      }
      su += __shfl_xor(su, 1);
      su += __shfl_xor(su, 2);
      su += __shfl_xor(su, 4);
      su += __shfl_xor(su, 8);
      inv[r] = 1.f / su;
    }
#pragma unroll
    for (int r = 0; r < 4; ++r) {
      const int rowP = wv * 16 + lk * 4 + r;
#pragma unroll
      for (int j = 0; j < 4; ++j) {
        const int col = j * 16 + lr;
        sP[rowP * 64 + (((col >> 3) ^ (rowP & 7)) << 3) + (col & 7)] = (f16)p[j][r];
      }
    }
  }

  __syncthreads();   // sVt ready

  // ---- fine PV -> sCat cols 0..31 ----
  {
    const int rowP = wv * 16 + lr;
    const f16x8 a0 = *reinterpret_cast<const f16x8*>(&sP[rowP * 64 + ((lk ^ (lr & 7)) << 3)]);
    const f16x8 a1 = *reinterpret_cast<const f16x8*>(&sP[rowP * 64 + (((4 + lk) ^ (lr & 7)) << 3)]);
#pragma unroll
    for (int n = 0; n < 2; ++n) {
      const int d = n * 16 + lr;
      const f16x8 b0 = *reinterpret_cast<const f16x8*>(&sVt[d * 64 + ((lk ^ (d & 7)) << 3)]);
      const f16x8 b1 = *reinterpret_cast<const f16x8*>(&sVt[d * 64 + (((4 + lk) ^ (d & 7)) << 3)]);
      f32x4 o = {};
      o = mfma_16x16x32(a0, b0, o);
      o = mfma_16x16x32(a1, b1, o);
#pragma unroll
      for (int r = 0; r < 4; ++r) {
        const int rowC = wv * 16 + lk * 4 + r;
        const int colC = n * 16 + lr;
        sCat[rowC * 64 + (((colC >> 3) ^ (rowC & 7)) << 3) + (colC & 7)] =
            (f16)(o[r] * inv[r]);
      }
    }
  }

  // ---- coarse QK^T (Kg from global) ----
#pragma unroll
  for (int j = 0; j < 4; ++j) {
    const f16x8 bk = *reinterpret_cast<const f16x8*>(
        Kgb + ((size_t)gs * 64 + j * 16 + lr) * 32 + lk * 8);
    f32x4 z = {};
    s[j] = mfma_16x16x32(aq, bk, z);
  }
  {
    const float* bt = gbf + h * 4096 + (wv * 16 + lk * 4) * 64;
#pragma unroll
    for (int r = 0; r < 4; ++r) {
      float m = -1e30f;
#pragma unroll
      for (int j = 0; j < 4; ++j) {
        const float v = s[j][r] * scale + bt[r * 64 + j * 16 + lr];
        p[j][r] = v;
        m = fmaxf(m, v);
      }
      m = fmaxf(m, __shfl_xor(m, 1));
      m = fmaxf(m, __shfl_xor(m, 2));
      m = fmaxf(m, __shfl_xor(m, 4));
      m = fmaxf(m, __shfl_xor(m, 8));
      float su = 0.f;
#pragma unroll
      for (int j = 0; j < 4; ++j) {
        const float e = __expf(p[j][r] - m);
        p[j][r] = e;
        su += e;
      }
      su += __shfl_xor(su, 1);
      su += __shfl_xor(su, 2);
      su += __shfl_xor(su, 4);
      su += __shfl_xor(su, 8);
      inv[r] = 1.f / su;
    }
#pragma unroll
    for (int r = 0; r < 4; ++r) {
      const int rowP = wv * 16 + lk * 4 + r;
#pragma unroll
      for (int j = 0; j < 4; ++j) {
        const int col = j * 16 + lr;
        sP[rowP * 64 + (((col >> 3) ^ (rowP & 7)) << 3) + (col & 7)] = (f16)p[j][r];
      }
    }
  }

  // ---- coarse PV (Vg from global, already transposed) -> sCat cols 32..63 ----
  {
    const int rowP = wv * 16 + lr;
    const f16x8 a0 = *reinterpret_cast<const f16x8*>(&sP[rowP * 64 + ((lk ^ (lr & 7)) << 3)]);
    const f16x8 a1 = *reinterpret_cast<const f16x8*>(&sP[rowP * 64 + (((4 + lk) ^ (lr & 7)) << 3)]);
#pragma unroll
    for (int n = 0; n < 2; ++n) {
      const f16* vp = Vgt + ((size_t)gs * 32 + n * 16 + lr) * 64 + lk * 8;
      const f16x8 b0 = *reinterpret_cast<const f16x8*>(vp);
      const f16x8 b1 = *reinterpret_cast<const f16x8*>(vp + 32);
      f32x4 o = {};
      o = mfma_16x16x32(a0, b0, o);
      o = mfma_16x16x32(a1, b1, o);
#pragma unroll
      for (int r = 0; r < 4; ++r) {
        const int rowC = wv * 16 + lk * 4 + r;
        const int colC = 32 + n * 16 + lr;
        sCat[rowC * 64 + (((colC >> 3) ^ (rowC & 7)) << 3) + (colC & 7)] =
            (f16)(o[r] * inv[r]);
      }
    }
  }

  // ---- store sCat (wave-private rows) -> cat, vectorized ----
  f16* catp = cat + ((size_t)b_ * 64) * 1024 + h * 64;
#pragma unroll
  for (int pass = 0; pass < 2; ++pass) {
    const int row = wv * 16 + pass * 8 + (l >> 3);
    const int c = l & 7;
    const f16x8 v = *reinterpret_cast<const f16x8*>(&sCat[row * 64 + ((c ^ (row & 7)) << 3)]);
    *reinterpret_cast<f16x8*>(catp + (size_t)row * 1024 + c * 8) = v;
  }
}

// ---------------------------------------------------------------------------
// Final GEMM (unchanged from round 5): 256x128 tile, BK=64, XCD swizzle.
// ---------------------------------------------------------------------------
__global__ __launch_bounds__(512) void k_gemm_final(const f16* __restrict__ A,
                                                    const f16* __restrict__ BT,
                                                    const float* __restrict__ bc,
                                                    float* __restrict__ out) {
  __shared__ f16 sA[16384];   // [256 rows][8 chunks x 8], chunk ^= row&7
  __shared__ f16 sB[8192];    // [128 rows][8 chunks x 8], chunk ^= row&7
  const int wid = (blockIdx.x & 7) * 128 + (blockIdx.x >> 3);
  const int br = wid >> 2, bn = wid & 3;
  const int t = threadIdx.x;
  const int wv = t >> 6, l = t & 63, lr = l & 15, lk = l >> 4;
  const int wvr = wv >> 1, wvc = wv & 1;

  f32x4 acc[4][4] = {};

  const int srow = t >> 3;
  const int sch = ((t & 7) ^ (srow & 7)) * 8;
  const f16* gA = A + (size_t)(br * 256 + srow) * 1024 + sch;
  const f16* gB = BT + (size_t)(bn * 128 + srow) * 1024 + sch;

  for (int kk = 0; kk < 16; ++kk) {
#pragma unroll
    for (int i = 0; i < 4; ++i)
      async_cp16(gA + (size_t)(i * 64) * 1024 + kk * 64, &sA[(i * 512 + t) * 8]);
#pragma unroll
    for (int i = 0; i < 2; ++i)
      async_cp16(gB + (size_t)(i * 64) * 1024 + kk * 64, &sB[(i * 512 + t) * 8]);
    __syncthreads();
    f16x8 af[4][2], bf[4][2];
#pragma unroll
    for (int m = 0; m < 4; ++m) {
      const int row = wvr * 64 + m * 16 + lr;
#pragma unroll
      for (int ks = 0; ks < 2; ++ks)
        af[m][ks] = *reinterpret_cast<const f16x8*>(
            &sA[row * 64 + (((ks * 4 + lk) ^ (row & 7)) << 3)]);
    }
#pragma unroll
    for (int n = 0; n < 4; ++n) {
      const int row = wvc * 64 + n * 16 + lr;
#pragma unroll
      for (int ks = 0; ks < 2; ++ks)
        bf[n][ks] = *reinterpret_cast<const f16x8*>(
            &sB[row * 64 + (((ks * 4 + lk) ^ (row & 7)) << 3)]);
    }
#pragma unroll
    for (int m = 0; m < 4; ++m)
#pragma unroll
      for (int n = 0; n < 4; ++n) {
        acc[m][n] = mfma_16x16x32(af[m][0], bf[n][0], acc[m][n]);
        acc[m][n] = mfma_16x16x32(af[m][1], bf[n][1], acc[m][n]);
      }
    __syncthreads();
  }

#pragma unroll
  for (int n = 0; n < 4; ++n) {
    const int col = bn * 128 + wvc * 64 + n * 16 + lr;
    const float bias = bc[col];
#pragma unroll
    for (int m = 0; m < 4; ++m)
#pragma unroll
      for (int r = 0; r < 4; ++r) {
        const int row = br * 256 + wvr * 64 + m * 16 + lk * 4 + r;
        out[(size_t)row * 512 + col] = acc[m][n][r] + bias;
      }
  }
}

// ---------------------------------------------------------------------------

extern "C" void kernel_launch(void* const* d_in, const int* in_sizes, int n_in,
                              void* d_out, int out_size, void* d_ws, size_t ws_size,
                              hipStream_t stream) {
  const float* x      = (const float*)d_in[0];
  const float* qkv_w  = (const float*)d_in[1];
  const float* qkv_b  = (const float*)d_in[2];
  const float* ltab   = (const float*)d_in[3];
  const float* gtab   = (const float*)d_in[4];
  const float* lpw    = (const float*)d_in[5];
  const float* lpb    = (const float*)d_in[6];
  const float* pool_w = (const float*)d_in[7];
  const float* pool_b = (const float*)d_in[8];
  const float* gpw    = (const float*)d_in[9];
  const float* gpb    = (const float*)d_in[10];
  const float* pfc_w  = (const float*)d_in[11];
  const float* pfc_b  = (const float*)d_in[12];
  float* out = (float*)d_out;

  char* ws = (char*)d_ws;
  f16*   qb   = (f16*)(ws + 0);
  f16*   kb   = (f16*)(ws + 67108864);
  f16*   vb   = (f16*)(ws + 134217728);
  f16*   cat  = (f16*)(ws + 201326592);
  f16*   qwT  = (f16*)(ws + 335544320);
  f16*   WcT  = (f16*)(ws + 337117184);
  float* bc   = (float*)(ws + 338165760);
  float* lbf  = (float*)(ws + 338167808);
  float* gbf  = (float*)(ws + 338429952);
  f16*   Kgb  = (f16*)(ws + 338692096);
  f16*   Vgt  = (f16*)(ws + 339740672);

  k_biastab<<<32, 256, 0, stream>>>(ltab, gtab, lbf, gbf);
  k_tqkvw<<<192, 256, 0, stream>>>(qkv_w, qwT);
  k_compose<<<64, 256, 0, stream>>>(lpw, gpw, pfc_w, WcT);
  k_bc_init<<<2, 256, 0, stream>>>(pfc_b, bc);
  k_bc_acc<<<32, 256, 0, stream>>>(lpb, gpb, pfc_w, bc);
  k_gemm_qkv<<<3072, 512, 0, stream>>>(x, qwT, qkv_b, pool_w, pool_b,
                                       qb, kb, vb, Kgb, Vgt);
  k_attn<<<16384, 256, 0, stream>>>(qb, kb, vb, Kgb, Vgt, lbf, gbf, cat);
  k_gemm_final<<<1024, 512, 0, stream>>>(cat, WcT, bc, out);
}